// Round 6
// baseline (749.766 us; speedup 1.0000x reference)
//
#include <hip/hip_runtime.h>

typedef _Float16 f16;
typedef _Float16 f16x8 __attribute__((ext_vector_type(8)));
typedef float    f32x4 __attribute__((ext_vector_type(4)));

#define BSZ 4
#define SL  2048
#define NK  24
#define DD  512
#define NPP 134   // p' = 2n+m+6 in [0,133]

typedef const void GV __attribute__((address_space(1)));
typedef void       LV __attribute__((address_space(3)));

__device__ __forceinline__ void gload_lds16(const void* gp, void* lp) {
  // dest = lp (wave-uniform) + lane*16
  __builtin_amdgcn_global_load_lds((GV*)gp, (LV*)lp, 16, 0, 0);
}

// ---------------- prep: A-fragment table
// afrag[i][p'][lane][j] = val(2047 - 16*(p'-6) - (lane&15) + 8*(lane>>4) + j)
// val(x) = (0<=x<2048) ? v[2047-x, i] * lam_i^0.25 : 0
__global__ void k_afrag(const float* __restrict__ eig_vals,
                        const float* __restrict__ eig_vecs,
                        f16* __restrict__ afrag) {
  int i = blockIdx.x, pp = blockIdx.y;
  int l = threadIdx.x;  // 64
  float sc = sqrtf(sqrtf(eig_vals[i]));
  int base = 2047 - 16 * (pp - 6) - (l & 15) + 8 * (l >> 4);
  f16 tmp[8];
#pragma unroll
  for (int j = 0; j < 8; ++j) {
    int x = base + j;
    float v = (x >= 0 && x < SL) ? eig_vecs[(size_t)(SL - 1 - x) * NK + i] * sc : 0.f;
    tmp[j] = (f16)v;
  }
  *(f16x8*)(afrag + (((size_t)i * NPP + pp) * 64 + l) * 8) = *(const f16x8*)tmp;
}

// ---------------- prep: ut[b][d][s] = (f16) u[b][s][d]
__global__ void k_tu(const float* __restrict__ u, f16* __restrict__ ut) {
  __shared__ float tile[32][33];
  int b = blockIdx.z;
  int s0 = blockIdx.x * 32, d0 = blockIdx.y * 32;
  int tx = threadIdx.x, ty = threadIdx.y;
#pragma unroll
  for (int r = 0; r < 4; ++r) {
    int s = s0 + ty * 4 + r;
    tile[ty * 4 + r][tx] = u[((size_t)b * SL + s) * DD + d0 + tx];
  }
  __syncthreads();
#pragma unroll
  for (int r = 0; r < 4; ++r) {
    int d = d0 + ty * 4 + r;
    ut[((size_t)b * DD + d) * SL + s0 + tx] = (f16)tile[tx][ty * 4 + r];
  }
}

// ---------------- prep: mht[e][k] = (f16) m_phi[k][e]   (B^T layout)
__global__ void k_tm(const float* __restrict__ mp, f16* __restrict__ mht) {
  __shared__ float tile[32][33];
  int k0 = blockIdx.x * 32, e0 = blockIdx.y * 32;
  int tx = threadIdx.x, ty = threadIdx.y;
#pragma unroll
  for (int r = 0; r < 4; ++r)
    tile[ty * 4 + r][tx] = mp[(size_t)(k0 + ty * 4 + r) * DD + e0 + tx];
  __syncthreads();
#pragma unroll
  for (int r = 0; r < 4; ++r)
    mht[(size_t)(e0 + ty * 4 + r) * (NK * DD) + k0 + tx] = (f16)tile[tx][ty * 4 + r];
}

// ---------------- phase A: causal Toeplitz conv -> xt[b][t][iL*512+d] (fp16)
// grid: x = 32 (tb 16 x dhalf 2), y = KI, z = b ; 256 threads (4 waves), wave 128t x 64d
// NO LDS, NO barriers. B-frags direct from ut (L2/L3-warm, depth-2 reg prefetch);
// A-frags register sliding window (slide 2/iter, depth-1). xt stores non-temporal.
__global__ __launch_bounds__(256, 2) void k_conv(
    const f16* __restrict__ ut, const f16* __restrict__ afrag,
    f16* __restrict__ xt, int KI, int ibase) {
  const int tid = threadIdx.x;
  const int tb = 15 - (blockIdx.x >> 1);   // reversed: big K-loops first
  const int dh = blockIdx.x & 1;
  const int iL = blockIdx.y;
  const int i  = ibase + iL;
  const int b  = blockIdx.z;
  const int t0 = tb * 128;

  const int w = tid >> 6, l = tid & 63;
  const int l15 = l & 15, lq = l >> 4;

  // F[pp] for this lane = afi + pp*512
  const f16* afi = afrag + ((size_t)i * NPP * 64 + l) * 8;
  // B[n] at iter it = *(pB0 + n*16*SL + it*32)
  const f16* pB0 = ut + (size_t)b * DD * SL
                     + (size_t)(dh * 256 + w * 64 + l15) * SL + lq * 8;

  f32x4 acc[8][4];
#pragma unroll
  for (int m = 0; m < 8; ++m)
#pragma unroll
    for (int n = 0; n < 4; ++n) acc[m][n] = (f32x4){0.f, 0.f, 0.f, 0.f};

  int pp0 = 8 * tb + 6;
  f16x8 A[8];
#pragma unroll
  for (int m = 0; m < 8; ++m)
    A[m] = *(const f16x8*)(afi + (size_t)(pp0 + m) * 512);
  f16x8 B[4], B1[4];
#pragma unroll
  for (int n = 0; n < 4; ++n) {
    B[n]  = *(const f16x8*)(pB0 + (size_t)n * 16 * SL);
    B1[n] = *(const f16x8*)(pB0 + 32 + (size_t)n * 16 * SL);
  }

  const int nIter = 4 * (tb + 1);
#pragma unroll 2
  for (int it = 0; it < nIter; ++it) {
    // ---- prefetch: A depth-1 (window slides by 2), B depth-2
    int ppn = pp0 - 2; if (ppn < 0) ppn = 0;   // tail clamp (values unused)
    const f16* f = afi + (size_t)ppn * 512;
    f16x8 a0n = *(const f16x8*)f;
    f16x8 a1n = *(const f16x8*)(f + 512);
    const f16* pB2 = pB0 + (it + 2) * 32;      // tail overshoot stays in-ws, unused
    f16x8 B2[4];
#pragma unroll
    for (int n = 0; n < 4; ++n)
      B2[n] = *(const f16x8*)(pB2 + (size_t)n * 16 * SL);

    // ---- compute current (operands loaded >= 1-2 iters ago)
    __builtin_amdgcn_s_setprio(1);
#pragma unroll
    for (int m = 0; m < 8; ++m)
#pragma unroll
      for (int n = 0; n < 4; ++n)
        acc[m][n] = __builtin_amdgcn_mfma_f32_16x16x32_f16(A[m], B[n], acc[m][n], 0, 0, 0);
    __builtin_amdgcn_s_setprio(0);

    // ---- rotate windows (static indices; regalloc renames)
    A[7] = A[5]; A[6] = A[4]; A[5] = A[3]; A[4] = A[2]; A[3] = A[1]; A[2] = A[0];
    A[0] = a0n;  A[1] = a1n;
#pragma unroll
    for (int n = 0; n < 4; ++n) { B[n] = B1[n]; B1[n] = B2[n]; }
    pp0 = ppn;
  }

  // store xt fp16 (non-temporal: don't evict ut/afrag from L2)
  // D frag: col=lane&15 (d), row=(lane>>4)*4+r (t)
  const size_t rowlen = (size_t)KI * DD;
  const int dbase = dh * 256 + w * 64;
#pragma unroll
  for (int m = 0; m < 8; ++m) {
    int t = t0 + m * 16 + lq * 4;
#pragma unroll
    for (int n = 0; n < 4; ++n) {
      int d = dbase + n * 16 + l15;
      f16* dst = xt + ((size_t)(b * SL + t) * KI + iL) * DD + d;
#pragma unroll
      for (int r = 0; r < 4; ++r)
        __builtin_nontemporal_store((f16)acc[m][n][r], dst + (size_t)r * rowlen);
    }
  }
}

// ---------------- phase B: out[8192][512] (+)= xt[8192][KI*512] @ mht^T
// BM=128, BN=128, BK=32; grid (4, 64); 256 thr, 4 waves (2x2), wave 64x64 (4x4 frags)
__global__ __launch_bounds__(256, 3) void k_gemm(
    const f16* __restrict__ xt, const f16* __restrict__ mht,
    float* __restrict__ out, int KI, int kc0, int beta) {
  __shared__ f16 at[2][128 * 32];     // 16 KB
  __shared__ f16 btl[2][128 * 32];    // 16 KB
  const int tid = threadIdx.x;
  const int n0 = blockIdx.x * 128;
  const int m0 = blockIdx.y * 128;
  const int w = tid >> 6, l = tid & 63;
  const int l15 = l & 15, lq = l >> 4;
  const int wr = w >> 1, wc = w & 1;
  const int KLEN = KI * DD;
  const int stage_col = ((l & 3) ^ ((l >> 3) & 3)) * 8;
  const int rd_x = (lq ^ ((l15 >> 1) & 3)) * 16;

  auto stage = [&](int buf, int k0) {
#pragma unroll
    for (int j = 0; j < 2; ++j) {
      int row = j * 64 + w * 16 + (l >> 2);
      gload_lds16(xt + (size_t)(m0 + row) * KLEN + k0 + stage_col,
                  &at[buf][j * 2048 + w * 512]);
      gload_lds16(mht + (size_t)(n0 + row) * (NK * DD) + kc0 + k0 + stage_col,
                  &btl[buf][j * 2048 + w * 512]);
    }
  };

  f32x4 acc[4][4];
#pragma unroll
  for (int m = 0; m < 4; ++m)
#pragma unroll
    for (int n = 0; n < 4; ++n) acc[m][n] = (f32x4){0.f, 0.f, 0.f, 0.f};

  const int nIter = KLEN / 32;
  stage(0, 0);
  __syncthreads();
  int cur = 0;

  for (int it = 0; it < nIter; ++it) {
    if (it + 1 < nIter) stage(cur ^ 1, (it + 1) * 32);

    f16x8 Af[4], Bf[4];
#pragma unroll
    for (int m = 0; m < 4; ++m) {
      int row = wr * 64 + m * 16 + l15;
      Af[m] = *(const f16x8*)((const char*)&at[cur][0] + row * 64 + rd_x);
    }
#pragma unroll
    for (int n = 0; n < 4; ++n) {
      int row = wc * 64 + n * 16 + l15;
      Bf[n] = *(const f16x8*)((const char*)&btl[cur][0] + row * 64 + rd_x);
    }

    __builtin_amdgcn_s_setprio(1);
#pragma unroll
    for (int m = 0; m < 4; ++m)
#pragma unroll
      for (int n = 0; n < 4; ++n)
        acc[m][n] = __builtin_amdgcn_mfma_f32_16x16x32_f16(Af[m], Bf[n], acc[m][n], 0, 0, 0);
    __builtin_amdgcn_s_setprio(0);

    __syncthreads();
    cur ^= 1;
  }

#pragma unroll
  for (int m = 0; m < 4; ++m) {
    int row = m0 + wr * 64 + m * 16 + lq * 4;
#pragma unroll
    for (int n = 0; n < 4; ++n) {
      int e = n0 + wc * 64 + n * 16 + l15;
      float* dst = out + (size_t)row * DD + e;
#pragma unroll
      for (int r = 0; r < 4; ++r) {
        float v = acc[m][n][r];
        if (beta) v += dst[(size_t)r * DD];
        dst[(size_t)r * DD] = v;
      }
    }
  }
}

extern "C" void kernel_launch(void* const* d_in, const int* in_sizes, int n_in,
                              void* d_out, int out_size, void* d_ws, size_t ws_size,
                              hipStream_t stream) {
  const float* u    = (const float*)d_in[0];  // [4,2048,512]
  const float* ev   = (const float*)d_in[1];  // [24]
  const float* evec = (const float*)d_in[2];  // [2048,24]
  const float* mp   = (const float*)d_in[3];  // [12288,512]
  float* out = (float*)d_out;
  char* ws = (char*)d_ws;

  const size_t UT_OFF  = 0;                        // 8,388,608 B
  const size_t MHT_OFF = 8388608;                  // 12,582,912 B
  const size_t AF_OFF  = 20971520;                 // 24*134*64*8*2 = 3,293,184 B
  const size_t XT_OFF  = 24264704;

  f16* ut    = (f16*)(ws + UT_OFF);
  f16* mht   = (f16*)(ws + MHT_OFF);
  f16* afrag = (f16*)(ws + AF_OFF);
  f16* xt    = (f16*)(ws + XT_OFF);

  // i-chunk: cap at 8 so the live set (ut+afrag+mht+xt+out ~106MB) stays L3-resident
  int KI = 1;
  const int cands[6] = {8, 6, 4, 3, 2, 1};
  for (int ci = 0; ci < 6; ++ci) {
    size_t need = XT_OFF + (size_t)cands[ci] * 8388608ull;
    if (need <= ws_size) { KI = cands[ci]; break; }
  }
  const int NC = NK / KI;

  k_afrag<<<dim3(24, NPP), 64, 0, stream>>>(ev, evec, afrag);
  k_tu<<<dim3(SL / 32, DD / 32, BSZ), dim3(32, 8), 0, stream>>>(u, ut);
  k_tm<<<dim3((NK * DD) / 32, DD / 32), dim3(32, 8), 0, stream>>>(mp, mht);

  for (int c = 0; c < NC; ++c) {
    k_conv<<<dim3(32, KI, BSZ), 256, 0, stream>>>(ut, afrag, xt, KI, c * KI);
    k_gemm<<<dim3(DD / 128, (BSZ * SL) / 128), 256, 0, stream>>>(
        xt, mht, out, KI, c * KI * DD, c > 0);
  }
}

// Round 7
// 502.729 us; speedup vs baseline: 1.4914x; 1.4914x over previous
//
#include <hip/hip_runtime.h>

typedef _Float16 f16;
typedef _Float16 f16x8 __attribute__((ext_vector_type(8)));
typedef float    f32x4 __attribute__((ext_vector_type(4)));

#define BSZ 4
#define SL  2048
#define NK  24
#define DD  512
#define NPP 134   // p' in [0,133]

typedef const void GV __attribute__((address_space(1)));
typedef void       LV __attribute__((address_space(3)));

__device__ __forceinline__ void gload_lds16(const void* gp, void* lp) {
  // dest = lp (wave-uniform) + lane*16
  __builtin_amdgcn_global_load_lds((GV*)gp, (LV*)lp, 16, 0, 0);
}

// ---------------- prep: A-fragment table
// afrag[i][p'][lane][j] = val(2047 - 16*(p'-6) - (lane&15) + 8*(lane>>4) + j)
// val(x) = (0<=x<2048) ? v[2047-x, i] * lam_i^0.25 : 0
__global__ void k_afrag(const float* __restrict__ eig_vals,
                        const float* __restrict__ eig_vecs,
                        f16* __restrict__ afrag) {
  int i = blockIdx.x, pp = blockIdx.y;
  int l = threadIdx.x;  // 64
  float sc = sqrtf(sqrtf(eig_vals[i]));
  int base = 2047 - 16 * (pp - 6) - (l & 15) + 8 * (l >> 4);
  f16 tmp[8];
#pragma unroll
  for (int j = 0; j < 8; ++j) {
    int x = base + j;
    float v = (x >= 0 && x < SL) ? eig_vecs[(size_t)(SL - 1 - x) * NK + i] * sc : 0.f;
    tmp[j] = (f16)v;
  }
  *(f16x8*)(afrag + (((size_t)i * NPP + pp) * 64 + l) * 8) = *(const f16x8*)tmp;
}

// ---------------- prep: ut[b][d][s] = (f16) u[b][s][d]
__global__ void k_tu(const float* __restrict__ u, f16* __restrict__ ut) {
  __shared__ float tile[32][33];
  int b = blockIdx.z;
  int s0 = blockIdx.x * 32, d0 = blockIdx.y * 32;
  int tx = threadIdx.x, ty = threadIdx.y;
#pragma unroll
  for (int r = 0; r < 4; ++r) {
    int s = s0 + ty * 4 + r;
    tile[ty * 4 + r][tx] = u[((size_t)b * SL + s) * DD + d0 + tx];
  }
  __syncthreads();
#pragma unroll
  for (int r = 0; r < 4; ++r) {
    int d = d0 + ty * 4 + r;
    ut[((size_t)b * DD + d) * SL + s0 + tx] = (f16)tile[tx][ty * 4 + r];
  }
}

// ---------------- prep: mht[e][k] = (f16) m_phi[k][e]   (B^T layout)
__global__ void k_tm(const float* __restrict__ mp, f16* __restrict__ mht) {
  __shared__ float tile[32][33];
  int k0 = blockIdx.x * 32, e0 = blockIdx.y * 32;
  int tx = threadIdx.x, ty = threadIdx.y;
#pragma unroll
  for (int r = 0; r < 4; ++r)
    tile[ty * 4 + r][tx] = mp[(size_t)(k0 + ty * 4 + r) * DD + e0 + tx];
  __syncthreads();
#pragma unroll
  for (int r = 0; r < 4; ++r)
    mht[(size_t)(e0 + ty * 4 + r) * (NK * DD) + k0 + tx] = (f16)tile[tx][ty * 4 + r];
}

// ---------------- phase A: causal Toeplitz conv -> xt[b][t][(ibase+iL)*512+d] (fp16)
// 256 threads (4 waves), wave tile 128t x 64d; two-barrier single-buffer B staging;
// A-frags direct from global table; NT xt stores.
// swz=1 (chunk of 8 i's, 1024 blocks): balanced decode tb=(lin>>6)&15 so each CU's
// sequential blocks get tb = {t, t+4, t+8, t+12} -> per-CU work 112..160 iters (was 16..1024).
__global__ __launch_bounds__(256, 2) void k_conv(
    const f16* __restrict__ ut, const f16* __restrict__ afrag,
    f16* __restrict__ xt, int KTOT, int ibase, int KIc, int swz) {
  __shared__ f16 bt[256 * 32];   // 16 KB
  const int tid = threadIdx.x;
  int tb, dh, iL, b;
  if (swz) {
    int lin = blockIdx.x + (blockIdx.y << 5) + (blockIdx.z << 8);
    tb = (lin >> 6) & 15;
    dh = lin & 1;
    iL = (lin >> 1) & 7;
    b  = (lin >> 4) & 3;
  } else {
    tb = 15 - (blockIdx.x >> 1);
    dh = blockIdx.x & 1;
    iL = blockIdx.y;
    b  = blockIdx.z;
  }
  const int i  = ibase + iL;
  const int t0 = tb * 128;

  const int w = tid >> 6, l = tid & 63;
  const int l15 = l & 15, lq = l >> 4;
  // staging/read swizzle pair (R4-proven, conflicts = 0)
  const int stage_col = ((l & 3) ^ ((l >> 3) & 3)) * 8;
  const int stage_row = l >> 2;
  const int rd_x = (lq ^ ((l15 >> 1) & 3)) * 16;

  const f16* utb = ut + (size_t)b * DD * SL;
  const f16* afi = afrag + ((size_t)i * NPP * 64 + l) * 8;

  f32x4 acc[8][4];
#pragma unroll
  for (int m = 0; m < 8; ++m)
#pragma unroll
    for (int n = 0; n < 4; ++n) acc[m][n] = (f32x4){0.f, 0.f, 0.f, 0.f};

  const int nIter = 4 * (tb + 1);
  int pp0 = 8 * tb + 6;

  for (int it = 0; it < nIter; ++it) {
    // stage bt[256][32] <- ut rows, source col pre-swizzled
    const int s0 = it * 32;
#pragma unroll
    for (int j = 0; j < 4; ++j) {
      int row = w * 64 + j * 16 + stage_row;
      gload_lds16(utb + (size_t)(dh * 256 + row) * SL + s0 + stage_col,
                  &bt[(w * 64 + j * 16) * 32]);
    }
    // A-frags for this iter (issued before the barrier; barrier wait covers latency)
    f16x8 A[8];
#pragma unroll
    for (int m = 0; m < 8; ++m)
      A[m] = *(const f16x8*)(afi + (size_t)(pp0 + m) * 512);

    __syncthreads();

    f16x8 B[4];
#pragma unroll
    for (int n = 0; n < 4; ++n) {
      int row = w * 64 + n * 16 + l15;
      B[n] = *(const f16x8*)((const char*)bt + row * 64 + rd_x);
    }

    __builtin_amdgcn_s_setprio(1);
#pragma unroll
    for (int m = 0; m < 8; ++m)
#pragma unroll
      for (int n = 0; n < 4; ++n)
        acc[m][n] = __builtin_amdgcn_mfma_f32_16x16x32_f16(A[m], B[n], acc[m][n], 0, 0, 0);
    __builtin_amdgcn_s_setprio(0);

    __syncthreads();
    pp0 -= 2;
  }

  // store xt fp16 (non-temporal). D frag: col=lane&15 (d), row=(lane>>4)*4+r (t)
  const size_t rowlen = (size_t)KTOT * DD;
  const int dbase = dh * 256 + w * 64;
#pragma unroll
  for (int m = 0; m < 8; ++m) {
    int t = t0 + m * 16 + lq * 4;
#pragma unroll
    for (int n = 0; n < 4; ++n) {
      int d = dbase + n * 16 + l15;
      f16* dst = xt + ((size_t)(b * SL + t) * KTOT + i) * DD + d;
#pragma unroll
      for (int r = 0; r < 4; ++r)
        __builtin_nontemporal_store((f16)acc[m][n][r], dst + (size_t)r * rowlen);
    }
  }
}

// ---------------- phase B: out[8192][512] (+)= xt[8192][AK] @ mht^T  (R2 structure)
// BM=64, BN=128, BK=64; grid (4, 128) = 512 blocks (2/CU); 256 thr, 4 waves (2m x 2n)
__global__ __launch_bounds__(256) void k_gemm(
    const f16* __restrict__ xt, const f16* __restrict__ mht,
    float* __restrict__ out, int AK, int KLEN, int kc0, int beta) {
  __shared__ f16 at[64 * 64];     // 8 KB
  __shared__ f16 btl[128 * 64];   // 16 KB
  const int tid = threadIdx.x;
  const int n0 = blockIdx.x * 128;
  const int m0 = blockIdx.y * 64;
  const int w = tid >> 6, l = tid & 63;
  const int l15 = l & 15, lq = l >> 4, k8 = lq << 3;
  const int wm = w >> 1, wn = w & 1;
  const int stage_col = ((l & 7) ^ (l >> 3)) * 8;
  const int stage_row = l >> 3;

  f32x4 acc[2][4];
#pragma unroll
  for (int m = 0; m < 2; ++m)
#pragma unroll
    for (int n = 0; n < 4; ++n) acc[m][n] = (f32x4){0.f, 0.f, 0.f, 0.f};

  for (int k0 = 0; k0 < KLEN; k0 += 64) {
    __syncthreads();
#pragma unroll
    for (int j = 0; j < 2; ++j) {  // A tile [64][64]
      int row = (w * 2 + j) * 8 + stage_row;
      gload_lds16(xt + (size_t)(m0 + row) * AK + k0 + stage_col,
                  at + (w * 2 + j) * 8 * 64);
    }
#pragma unroll
    for (int j = 0; j < 4; ++j) {  // B tile [128][64]
      int row = (w * 4 + j) * 8 + stage_row;
      gload_lds16(mht + (size_t)(n0 + row) * (NK * DD) + kc0 + k0 + stage_col,
                  btl + (w * 4 + j) * 8 * 64);
    }
    __syncthreads();
#pragma unroll
    for (int ks = 0; ks < 2; ++ks) {
      f16x8 Bf[4];
#pragma unroll
      for (int n = 0; n < 4; ++n) {
        int lin = (wn * 64 + n * 16 + l15) * 128 + ks * 64 + lq * 16;
        lin ^= (l15 & 7) << 4;
        Bf[n] = *(const f16x8*)((const char*)btl + lin);
      }
#pragma unroll
      for (int m = 0; m < 2; ++m) {
        int lin = (wm * 32 + m * 16 + l15) * 128 + ks * 64 + lq * 16;
        lin ^= (l15 & 7) << 4;
        f16x8 Af = *(const f16x8*)((const char*)at + lin);
#pragma unroll
        for (int n = 0; n < 4; ++n)
          acc[m][n] = __builtin_amdgcn_mfma_f32_16x16x32_f16(Af, Bf[n], acc[m][n], 0, 0, 0);
      }
    }
  }

#pragma unroll
  for (int m = 0; m < 2; ++m) {
    int row = m0 + wm * 32 + m * 16 + lq * 4;
#pragma unroll
    for (int n = 0; n < 4; ++n) {
      int e = n0 + wn * 64 + n * 16 + l15;
      float* dst = out + (size_t)row * DD + e;
#pragma unroll
      for (int r = 0; r < 4; ++r) {
        float v = acc[m][n][r];
        if (beta) v += dst[(size_t)r * DD];
        dst[(size_t)r * DD] = v;
      }
    }
  }
}

extern "C" void kernel_launch(void* const* d_in, const int* in_sizes, int n_in,
                              void* d_out, int out_size, void* d_ws, size_t ws_size,
                              hipStream_t stream) {
  const float* u    = (const float*)d_in[0];  // [4,2048,512]
  const float* ev   = (const float*)d_in[1];  // [24]
  const float* evec = (const float*)d_in[2];  // [2048,24]
  const float* mp   = (const float*)d_in[3];  // [12288,512]
  float* out = (float*)d_out;
  char* ws = (char*)d_ws;

  const size_t UT_OFF  = 0;                        // 8,388,608 B
  const size_t MHT_OFF = 8388608;                  // 12,582,912 B
  const size_t AF_OFF  = 20971520;                 // 24*134*64*8*2 = 3,293,184 B
  const size_t XT_OFF  = 24264704;

  f16* ut    = (f16*)(ws + UT_OFF);
  f16* mht   = (f16*)(ws + MHT_OFF);
  f16* afrag = (f16*)(ws + AF_OFF);
  f16* xt    = (f16*)(ws + XT_OFF);

  // KTOT = i's resident in xt (prefer all 24 -> single gemm pass)
  int KTOT = 1;
  const int cands[7] = {24, 8, 6, 4, 3, 2, 1};
  for (int ci = 0; ci < 7; ++ci) {
    size_t need = XT_OFF + (size_t)cands[ci] * 8388608ull;
    if (need <= ws_size) { KTOT = cands[ci]; break; }
  }

  k_afrag<<<dim3(24, NPP), 64, 0, stream>>>(ev, evec, afrag);
  k_tu<<<dim3(SL / 32, DD / 32, BSZ), dim3(32, 8), 0, stream>>>(u, ut);
  k_tm<<<dim3((NK * DD) / 32, DD / 32), dim3(32, 8), 0, stream>>>(mp, mht);

  if (KTOT >= 8) {
    const int KIc = 8;  // conv chunk (keeps conv live-set L3-friendly)
    for (int ib = 0; ib < KTOT; ib += KIc)
      k_conv<<<dim3(32, KIc, BSZ), 256, 0, stream>>>(ut, afrag, xt, KTOT, ib, KIc, 1);
    // gemm: full resident K in one pass per KTOT-chunk of the 24
    for (int c = 0; c < NK / KTOT; ++c) {
      if (c > 0)  // re-run conv for next resident chunk (only if KTOT < 24)
        for (int ib = 0; ib < KTOT; ib += KIc)
          k_conv<<<dim3(32, KIc, BSZ), 256, 0, stream>>>(ut, afrag, xt, KTOT,
                                                         ib, KIc, 1);
      k_gemm<<<dim3(DD / 128, (BSZ * SL) / 64), 256, 0, stream>>>(
          xt, mht, out, KTOT * DD, KTOT * DD, c * KTOT * DD, c > 0);
    }
  } else {
    const int NC = NK / KTOT;
    for (int c = 0; c < NC; ++c) {
      k_conv<<<dim3(32, KTOT, BSZ), 256, 0, stream>>>(ut, afrag, xt, KTOT,
                                                      0, KTOT, 0);
      k_gemm<<<dim3(DD / 128, (BSZ * SL) / 64), 256, 0, stream>>>(
          xt, mht, out, KTOT * DD, KTOT * DD, c * KTOT * DD, c > 0);
    }
  }
}

// Round 8
// 466.035 us; speedup vs baseline: 1.6088x; 1.0787x over previous
//
#include <hip/hip_runtime.h>

typedef _Float16 f16;
typedef _Float16 f16x8 __attribute__((ext_vector_type(8)));
typedef float    f32x4 __attribute__((ext_vector_type(4)));

#define BSZ 4
#define SL  2048
#define NK  24
#define DD  512
#define NPP 134   // p' in [0,133]
#define KI  8     // i's per chunk (xt chunk 67 MB -> L3-resident)

typedef const void GV __attribute__((address_space(1)));
typedef void       LV __attribute__((address_space(3)));

__device__ __forceinline__ void gload_lds16(const void* gp, void* lp) {
  // dest = lp (wave-uniform) + lane*16
  __builtin_amdgcn_global_load_lds((GV*)gp, (LV*)lp, 16, 0, 0);
}

// ---------------- prep: A-fragment table
// afrag[i][p'][lane][j] = val(2047 - 16*(p'-6) - (lane&15) + 8*(lane>>4) + j)
// val(x) = (0<=x<2048) ? v[2047-x, i] * lam_i^0.25 : 0
__global__ void k_afrag(const float* __restrict__ eig_vals,
                        const float* __restrict__ eig_vecs,
                        f16* __restrict__ afrag) {
  int i = blockIdx.x, pp = blockIdx.y;
  int l = threadIdx.x;  // 64
  float sc = sqrtf(sqrtf(eig_vals[i]));
  int base = 2047 - 16 * (pp - 6) - (l & 15) + 8 * (l >> 4);
  f16 tmp[8];
#pragma unroll
  for (int j = 0; j < 8; ++j) {
    int x = base + j;
    float v = (x >= 0 && x < SL) ? eig_vecs[(size_t)(SL - 1 - x) * NK + i] * sc : 0.f;
    tmp[j] = (f16)v;
  }
  *(f16x8*)(afrag + (((size_t)i * NPP + pp) * 64 + l) * 8) = *(const f16x8*)tmp;
}

// ---------------- prep: ut[b][d][s] = (f16) u[b][s][d]
__global__ void k_tu(const float* __restrict__ u, f16* __restrict__ ut) {
  __shared__ float tile[32][33];
  int b = blockIdx.z;
  int s0 = blockIdx.x * 32, d0 = blockIdx.y * 32;
  int tx = threadIdx.x, ty = threadIdx.y;
#pragma unroll
  for (int r = 0; r < 4; ++r) {
    int s = s0 + ty * 4 + r;
    tile[ty * 4 + r][tx] = u[((size_t)b * SL + s) * DD + d0 + tx];
  }
  __syncthreads();
#pragma unroll
  for (int r = 0; r < 4; ++r) {
    int d = d0 + ty * 4 + r;
    ut[((size_t)b * DD + d) * SL + s0 + tx] = (f16)tile[tx][ty * 4 + r];
  }
}

// ---------------- prep: mht[e][k] = (f16) m_phi[k][e]   (B^T layout)
__global__ void k_tm(const float* __restrict__ mp, f16* __restrict__ mht) {
  __shared__ float tile[32][33];
  int k0 = blockIdx.x * 32, e0 = blockIdx.y * 32;
  int tx = threadIdx.x, ty = threadIdx.y;
#pragma unroll
  for (int r = 0; r < 4; ++r)
    tile[ty * 4 + r][tx] = mp[(size_t)(k0 + ty * 4 + r) * DD + e0 + tx];
  __syncthreads();
#pragma unroll
  for (int r = 0; r < 4; ++r)
    mht[(size_t)(e0 + ty * 4 + r) * (NK * DD) + k0 + tx] = (f16)tile[tx][ty * 4 + r];
}

// ---------------- phase A: causal Toeplitz conv -> xt[b][t][iL*512+d] (fp16, chunk-local)
// grid (32, KI, 4); 256 threads (4 waves), wave tile 128t x 64d.
// Balanced decode: lin = x+32y+256z, tb=(lin>>6)&15 -> each CU's sequential blocks
// get tb = {t, t+4, t+8, t+12} (per-CU 112..160 iters).
// Double-buffered B staging, ONE barrier/iter; A-frags direct from global table.
__global__ __launch_bounds__(256, 2) void k_conv(
    const f16* __restrict__ ut, const f16* __restrict__ afrag,
    f16* __restrict__ xt, int ibase) {
  __shared__ f16 bt[2][256 * 32];   // 32 KB
  const int tid = threadIdx.x;
  const int lin = blockIdx.x + (blockIdx.y << 5) + (blockIdx.z << 8);
  const int tb = (lin >> 6) & 15;
  const int dh = lin & 1;
  const int iL = (lin >> 1) & 7;
  const int b  = (lin >> 4) & 3;
  const int iG = ibase + iL;
  const int t0 = tb * 128;

  const int w = tid >> 6, l = tid & 63;
  const int l15 = l & 15, lq = l >> 4;
  // staging/read swizzle pair (R4-proven, conflicts = 0)
  const int stage_col = ((l & 3) ^ ((l >> 3) & 3)) * 8;
  const int stage_row = l >> 2;
  const int rd_x = (lq ^ ((l15 >> 1) & 3)) * 16;

  const f16* utb = ut + (size_t)b * DD * SL;
  const f16* afi = afrag + ((size_t)iG * NPP * 64 + l) * 8;

  auto stage = [&](int buf, int s0) {
#pragma unroll
    for (int j = 0; j < 4; ++j) {
      int row = w * 64 + j * 16 + stage_row;
      gload_lds16(utb + (size_t)(dh * 256 + row) * SL + s0 + stage_col,
                  &bt[buf][(w * 64 + j * 16) * 32]);
    }
  };

  f32x4 acc[8][4];
#pragma unroll
  for (int m = 0; m < 8; ++m)
#pragma unroll
    for (int n = 0; n < 4; ++n) acc[m][n] = (f32x4){0.f, 0.f, 0.f, 0.f};

  const int nIter = 4 * (tb + 1);
  int pp0 = 8 * tb + 6;
  stage(0, 0);
  __syncthreads();
  int cur = 0;

  for (int it = 0; it < nIter; ++it) {
    if (it + 1 < nIter) stage(cur ^ 1, (it + 1) * 32);  // prefetch flies under MFMA

    f16x8 A[8];
#pragma unroll
    for (int m = 0; m < 8; ++m)
      A[m] = *(const f16x8*)(afi + (size_t)(pp0 + m) * 512);

    f16x8 B[4];
#pragma unroll
    for (int n = 0; n < 4; ++n) {
      int row = w * 64 + n * 16 + l15;
      B[n] = *(const f16x8*)((const char*)&bt[cur][0] + row * 64 + rd_x);
    }

    __builtin_amdgcn_s_setprio(1);
#pragma unroll
    for (int m = 0; m < 8; ++m)
#pragma unroll
      for (int n = 0; n < 4; ++n)
        acc[m][n] = __builtin_amdgcn_mfma_f32_16x16x32_f16(A[m], B[n], acc[m][n], 0, 0, 0);
    __builtin_amdgcn_s_setprio(0);

    __syncthreads();   // drains prefetch vmcnt + protects dbuf WAR
    cur ^= 1;
    pp0 -= 2;
  }

  // store xt fp16 (REGULAR stores: keep chunk L2/L3-hot for the following gemm)
  // D frag: col=lane&15 (d), row=(lane>>4)*4+r (t)
  const size_t rowlen = (size_t)KI * DD;
  const int dbase = dh * 256 + w * 64;
#pragma unroll
  for (int m = 0; m < 8; ++m) {
    int t = t0 + m * 16 + lq * 4;
#pragma unroll
    for (int n = 0; n < 4; ++n) {
      int d = dbase + n * 16 + l15;
      f16* dst = xt + ((size_t)(b * SL + t) * KI + iL) * DD + d;
#pragma unroll
      for (int r = 0; r < 4; ++r)
        dst[(size_t)r * rowlen] = (f16)acc[m][n][r];
    }
  }
}

// ---------------- phase B: out[8192][512] (+)= xt[8192][4096] @ mht[:, kc0:kc0+4096]^T
// BM=64, BN=128, BK=64; grid (4, 128) = 512 blocks (2/CU); 256 thr, 4 waves (2m x 2n)
__global__ __launch_bounds__(256) void k_gemm(
    const f16* __restrict__ xt, const f16* __restrict__ mht,
    float* __restrict__ out, int kc0, int beta) {
  __shared__ f16 at[64 * 64];     // 8 KB
  __shared__ f16 btl[128 * 64];   // 16 KB
  const int AK = KI * DD;         // 4096
  const int tid = threadIdx.x;
  const int n0 = blockIdx.x * 128;
  const int m0 = blockIdx.y * 64;
  const int w = tid >> 6, l = tid & 63;
  const int l15 = l & 15, lq = l >> 4;
  const int wm = w >> 1, wn = w & 1;
  const int stage_col = ((l & 7) ^ (l >> 3)) * 8;
  const int stage_row = l >> 3;

  f32x4 acc[2][4];
#pragma unroll
  for (int m = 0; m < 2; ++m)
#pragma unroll
    for (int n = 0; n < 4; ++n) acc[m][n] = (f32x4){0.f, 0.f, 0.f, 0.f};

  for (int k0 = 0; k0 < AK; k0 += 64) {
    __syncthreads();
#pragma unroll
    for (int j = 0; j < 2; ++j) {  // A tile [64][64]
      int row = (w * 2 + j) * 8 + stage_row;
      gload_lds16(xt + (size_t)(m0 + row) * AK + k0 + stage_col,
                  at + (w * 2 + j) * 8 * 64);
    }
#pragma unroll
    for (int j = 0; j < 4; ++j) {  // B tile [128][64]
      int row = (w * 4 + j) * 8 + stage_row;
      gload_lds16(mht + (size_t)(n0 + row) * (NK * DD) + kc0 + k0 + stage_col,
                  btl + (w * 4 + j) * 8 * 64);
    }
    __syncthreads();
#pragma unroll
    for (int ks = 0; ks < 2; ++ks) {
      f16x8 Bf[4];
#pragma unroll
      for (int n = 0; n < 4; ++n) {
        int lin2 = (wn * 64 + n * 16 + l15) * 128 + ks * 64 + lq * 16;
        lin2 ^= (l15 & 7) << 4;
        Bf[n] = *(const f16x8*)((const char*)btl + lin2);
      }
#pragma unroll
      for (int m = 0; m < 2; ++m) {
        int lin2 = (wm * 32 + m * 16 + l15) * 128 + ks * 64 + lq * 16;
        lin2 ^= (l15 & 7) << 4;
        f16x8 Af = *(const f16x8*)((const char*)at + lin2);
#pragma unroll
        for (int n = 0; n < 4; ++n)
          acc[m][n] = __builtin_amdgcn_mfma_f32_16x16x32_f16(Af, Bf[n], acc[m][n], 0, 0, 0);
      }
    }
  }

#pragma unroll
  for (int m = 0; m < 2; ++m) {
    int row = m0 + wm * 32 + m * 16 + lq * 4;
#pragma unroll
    for (int n = 0; n < 4; ++n) {
      int e = n0 + wn * 64 + n * 16 + l15;
      float* dst = out + (size_t)row * DD + e;
#pragma unroll
      for (int r = 0; r < 4; ++r) {
        float v = acc[m][n][r];
        if (beta) v += dst[(size_t)r * DD];
        dst[(size_t)r * DD] = v;
      }
    }
  }
}

extern "C" void kernel_launch(void* const* d_in, const int* in_sizes, int n_in,
                              void* d_out, int out_size, void* d_ws, size_t ws_size,
                              hipStream_t stream) {
  const float* u    = (const float*)d_in[0];  // [4,2048,512]
  const float* ev   = (const float*)d_in[1];  // [24]
  const float* evec = (const float*)d_in[2];  // [2048,24]
  const float* mp   = (const float*)d_in[3];  // [12288,512]
  float* out = (float*)d_out;
  char* ws = (char*)d_ws;

  const size_t UT_OFF  = 0;                        // 8,388,608 B
  const size_t MHT_OFF = 8388608;                  // 12,582,912 B
  const size_t AF_OFF  = 20971520;                 // 24*134*64*8*2 = 3,293,184 B
  const size_t XT_OFF  = 24264704;                 // + 8*8,388,608 = 91.4 MB total

  f16* ut    = (f16*)(ws + UT_OFF);
  f16* mht   = (f16*)(ws + MHT_OFF);
  f16* afrag = (f16*)(ws + AF_OFF);
  f16* xt    = (f16*)(ws + XT_OFF);

  k_afrag<<<dim3(24, NPP), 64, 0, stream>>>(ev, evec, afrag);
  k_tu<<<dim3(SL / 32, DD / 32, BSZ), dim3(32, 8), 0, stream>>>(u, ut);
  k_tm<<<dim3((NK * DD) / 32, DD / 32), dim3(32, 8), 0, stream>>>(mp, mht);

  for (int c = 0; c < NK / KI; ++c) {
    k_conv<<<dim3(32, KI, BSZ), 256, 0, stream>>>(ut, afrag, xt, c * KI);
    k_gemm<<<dim3(DD / 128, (BSZ * SL) / 64), 256, 0, stream>>>(
        xt, mht, out, c * KI * DD, c > 0);
  }
}

// Round 9
// 428.486 us; speedup vs baseline: 1.7498x; 1.0876x over previous
//
#include <hip/hip_runtime.h>

typedef _Float16 f16;
typedef _Float16 f16x8 __attribute__((ext_vector_type(8)));
typedef float    f32x4 __attribute__((ext_vector_type(4)));

#define BSZ 4
#define SL  2048
#define NK  24
#define DD  512
#define NPP 134   // p' in [0,133]
#define KI  8     // i's per chunk (xt chunk 67 MB -> L3-resident)

typedef const void GV __attribute__((address_space(1)));
typedef void       LV __attribute__((address_space(3)));

__device__ __forceinline__ void gload_lds16(const void* gp, void* lp) {
  // dest = lp (wave-uniform) + lane*16
  __builtin_amdgcn_global_load_lds((GV*)gp, (LV*)lp, 16, 0, 0);
}

// ---------------- prep: A-fragment table
// afrag[i][p'][lane][j] = val(2047 - 16*(p'-6) - (lane&15) + 8*(lane>>4) + j)
// val(x) = (0<=x<2048) ? v[2047-x, i] * lam_i^0.25 : 0
__global__ void k_afrag(const float* __restrict__ eig_vals,
                        const float* __restrict__ eig_vecs,
                        f16* __restrict__ afrag) {
  int i = blockIdx.x, pp = blockIdx.y;
  int l = threadIdx.x;  // 64
  float sc = sqrtf(sqrtf(eig_vals[i]));
  int base = 2047 - 16 * (pp - 6) - (l & 15) + 8 * (l >> 4);
  f16 tmp[8];
#pragma unroll
  for (int j = 0; j < 8; ++j) {
    int x = base + j;
    float v = (x >= 0 && x < SL) ? eig_vecs[(size_t)(SL - 1 - x) * NK + i] * sc : 0.f;
    tmp[j] = (f16)v;
  }
  *(f16x8*)(afrag + (((size_t)i * NPP + pp) * 64 + l) * 8) = *(const f16x8*)tmp;
}

// ---------------- prep: ut[b][d][s] = (f16) u[b][s][d]
__global__ void k_tu(const float* __restrict__ u, f16* __restrict__ ut) {
  __shared__ float tile[32][33];
  int b = blockIdx.z;
  int s0 = blockIdx.x * 32, d0 = blockIdx.y * 32;
  int tx = threadIdx.x, ty = threadIdx.y;
#pragma unroll
  for (int r = 0; r < 4; ++r) {
    int s = s0 + ty * 4 + r;
    tile[ty * 4 + r][tx] = u[((size_t)b * SL + s) * DD + d0 + tx];
  }
  __syncthreads();
#pragma unroll
  for (int r = 0; r < 4; ++r) {
    int d = d0 + ty * 4 + r;
    ut[((size_t)b * DD + d) * SL + s0 + tx] = (f16)tile[tx][ty * 4 + r];
  }
}

// ---------------- prep: mht[e][k] = (f16) m_phi[k][e]   (B^T layout)
__global__ void k_tm(const float* __restrict__ mp, f16* __restrict__ mht) {
  __shared__ float tile[32][33];
  int k0 = blockIdx.x * 32, e0 = blockIdx.y * 32;
  int tx = threadIdx.x, ty = threadIdx.y;
#pragma unroll
  for (int r = 0; r < 4; ++r)
    tile[ty * 4 + r][tx] = mp[(size_t)(k0 + ty * 4 + r) * DD + e0 + tx];
  __syncthreads();
#pragma unroll
  for (int r = 0; r < 4; ++r)
    mht[(size_t)(e0 + ty * 4 + r) * (NK * DD) + k0 + tx] = (f16)tile[tx][ty * 4 + r];
}

// ---------------- phase A: causal Toeplitz conv -> xt[b][t][iL*512+d] (fp16, chunk-local)
// grid (32, KI, 4); 256 threads (4 waves), wave tile 128t x 64d.
// Balanced decode tb=(lin>>6)&15. 3-buffer LDS pipeline, depth-2 prefetch,
// ONE raw s_barrier/iter with counted vmcnt (prefetch stays in flight across barrier).
// Invariants: reads of buf p precede barrier k; p re-written only after barrier k (3 iters later).
__global__ __launch_bounds__(256, 2) void k_conv(
    const f16* __restrict__ ut, const f16* __restrict__ afrag,
    f16* __restrict__ xt, int ibase) {
  __shared__ f16 bt[3][256 * 32];   // 48 KB
  const int tid = threadIdx.x;
  const int lin = blockIdx.x + (blockIdx.y << 5) + (blockIdx.z << 8);
  const int tb = (lin >> 6) & 15;
  const int dh = lin & 1;
  const int iL = (lin >> 1) & 7;
  const int b  = (lin >> 4) & 3;
  const int iG = ibase + iL;
  const int t0 = tb * 128;

  const int w = tid >> 6, l = tid & 63;
  const int l15 = l & 15, lq = l >> 4;
  // staging/read swizzle pair (R4-proven, conflicts = 0)
  const int stage_col = ((l & 3) ^ ((l >> 3) & 3)) * 8;
  const int stage_row = l >> 2;
  const int rd_x = (lq ^ ((l15 >> 1) & 3)) * 16;

  const f16* utb = ut + (size_t)b * DD * SL;
  const f16* afi = afrag + ((size_t)iG * NPP * 64 + l) * 8;

  auto stage = [&](int buf, int s0) {
#pragma unroll
    for (int j = 0; j < 4; ++j) {
      int row = w * 64 + j * 16 + stage_row;
      gload_lds16(utb + (size_t)(dh * 256 + row) * SL + s0 + stage_col,
                  &bt[buf][(w * 64 + j * 16) * 32]);
    }
  };

  f32x4 acc[8][4];
#pragma unroll
  for (int m = 0; m < 8; ++m)
#pragma unroll
    for (int n = 0; n < 4; ++n) acc[m][n] = (f32x4){0.f, 0.f, 0.f, 0.f};

  const int nIter = 4 * (tb + 1);   // >= 4
  int pp0 = 8 * tb + 6;

  // prologue: fill buffers 0,1; ensure buf0 visible to all waves
  stage(0, 0);
  stage(1, 32);
  asm volatile("s_waitcnt vmcnt(4)" ::: "memory");   // buf0 drained, buf1 in flight
  __builtin_amdgcn_s_barrier();
  __builtin_amdgcn_sched_barrier(0);

  for (int it = 0; it < nIter; ++it) {
    const int bufR = it % 3;
    // B frags from LDS (buf staged 2 iters ago; drained by prev iter's vmcnt+barrier)
    f16x8 B[4];
#pragma unroll
    for (int n = 0; n < 4; ++n) {
      int row = w * 64 + n * 16 + l15;
      B[n] = *(const f16x8*)((const char*)&bt[bufR][0] + row * 64 + rd_x);
    }
    // A frags for THIS iter (global, L2-hot; within newest-12 window, compiler waits before MFMA)
    f16x8 A[8];
#pragma unroll
    for (int m = 0; m < 8; ++m)
      A[m] = *(const f16x8*)(afi + (size_t)(pp0 + m) * 512);

    // depth-2 prefetch into the buffer read at it-1 (safe: all waves passed barrier it-1)
    if (it + 2 < nIter) stage((it + 2) % 3, (it + 2) * 32);

    // leave newest 12 (this iter's 4 stage + 8 A) in flight; older stages drained
    asm volatile("s_waitcnt vmcnt(12)" ::: "memory");
    __builtin_amdgcn_s_barrier();
    __builtin_amdgcn_sched_barrier(0);

    __builtin_amdgcn_s_setprio(1);
#pragma unroll
    for (int m = 0; m < 8; ++m)
#pragma unroll
      for (int n = 0; n < 4; ++n)
        acc[m][n] = __builtin_amdgcn_mfma_f32_16x16x32_f16(A[m], B[n], acc[m][n], 0, 0, 0);
    __builtin_amdgcn_s_setprio(0);
    pp0 -= 2;
  }

  // store xt fp16 (regular stores: keep chunk L3-hot for the following gemm)
  // D frag: col=lane&15 (d), row=(lane>>4)*4+r (t)
  const size_t rowlen = (size_t)KI * DD;
  const int dbase = dh * 256 + w * 64;
#pragma unroll
  for (int m = 0; m < 8; ++m) {
    int t = t0 + m * 16 + lq * 4;
#pragma unroll
    for (int n = 0; n < 4; ++n) {
      int d = dbase + n * 16 + l15;
      f16* dst = xt + ((size_t)(b * SL + t) * KI + iL) * DD + d;
#pragma unroll
      for (int r = 0; r < 4; ++r)
        dst[(size_t)r * rowlen] = (f16)acc[m][n][r];
    }
  }
}

// ---------------- phase B: out[8192][512] (+)= xt[8192][4096] @ mht[:, kc0:+4096]^T
// BM=64, BN=128, BK=64; grid (4, 128) = 512 blocks (2/CU); 256 thr, 4 waves (2m x 2n)
// Same 3-buffer counted-vmcnt pipeline (6 loads/stage -> vmcnt(6)).
__global__ __launch_bounds__(256, 2) void k_gemm(
    const f16* __restrict__ xt, const f16* __restrict__ mht,
    float* __restrict__ out, int kc0, int beta) {
  __shared__ f16 at[3][64 * 64];      // 24 KB
  __shared__ f16 btl[3][128 * 64];    // 48 KB
  const int AK = KI * DD;             // 4096
  const int tid = threadIdx.x;
  const int n0 = blockIdx.x * 128;
  const int m0 = blockIdx.y * 64;
  const int w = tid >> 6, l = tid & 63;
  const int l15 = l & 15, lq = l >> 4;
  const int wm = w >> 1, wn = w & 1;
  const int stage_col = ((l & 7) ^ (l >> 3)) * 8;
  const int stage_row = l >> 3;

  auto stage = [&](int buf, int k0) {
#pragma unroll
    for (int j = 0; j < 2; ++j) {  // A tile [64][64]
      int row = (w * 2 + j) * 8 + stage_row;
      gload_lds16(xt + (size_t)(m0 + row) * AK + k0 + stage_col,
                  &at[buf][(w * 2 + j) * 8 * 64]);
    }
#pragma unroll
    for (int j = 0; j < 4; ++j) {  // B tile [128][64]
      int row = (w * 4 + j) * 8 + stage_row;
      gload_lds16(mht + (size_t)(n0 + row) * (NK * DD) + kc0 + k0 + stage_col,
                  &btl[buf][(w * 4 + j) * 8 * 64]);
    }
  };

  f32x4 acc[2][4];
#pragma unroll
  for (int m = 0; m < 2; ++m)
#pragma unroll
    for (int n = 0; n < 4; ++n) acc[m][n] = (f32x4){0.f, 0.f, 0.f, 0.f};

  const int nIter = AK / 64;   // 64
  stage(0, 0);
  stage(1, 64);
  asm volatile("s_waitcnt vmcnt(6)" ::: "memory");
  __builtin_amdgcn_s_barrier();
  __builtin_amdgcn_sched_barrier(0);

  for (int it = 0; it < nIter; ++it) {
    const int bufR = it % 3;
    f16x8 Af[2][2], Bf[2][4];
#pragma unroll
    for (int ks = 0; ks < 2; ++ks) {
#pragma unroll
      for (int m = 0; m < 2; ++m) {
        int lin2 = (wm * 32 + m * 16 + l15) * 128 + ks * 64 + lq * 16;
        lin2 ^= (l15 & 7) << 4;
        Af[ks][m] = *(const f16x8*)((const char*)&at[bufR][0] + lin2);
      }
#pragma unroll
      for (int n = 0; n < 4; ++n) {
        int lin2 = (wn * 64 + n * 16 + l15) * 128 + ks * 64 + lq * 16;
        lin2 ^= (l15 & 7) << 4;
        Bf[ks][n] = *(const f16x8*)((const char*)&btl[bufR][0] + lin2);
      }
    }

    if (it + 2 < nIter) stage((it + 2) % 3, (it + 2) * 64);

    asm volatile("s_waitcnt vmcnt(6)" ::: "memory");
    __builtin_amdgcn_s_barrier();
    __builtin_amdgcn_sched_barrier(0);

    __builtin_amdgcn_s_setprio(1);
#pragma unroll
    for (int ks = 0; ks < 2; ++ks)
#pragma unroll
      for (int m = 0; m < 2; ++m)
#pragma unroll
        for (int n = 0; n < 4; ++n)
          acc[m][n] = __builtin_amdgcn_mfma_f32_16x16x32_f16(
              Af[ks][m], Bf[ks][n], acc[m][n], 0, 0, 0);
    __builtin_amdgcn_s_setprio(0);
  }

#pragma unroll
  for (int m = 0; m < 2; ++m) {
    int row = m0 + wm * 32 + m * 16 + lq * 4;
#pragma unroll
    for (int n = 0; n < 4; ++n) {
      int e = n0 + wn * 64 + n * 16 + l15;
      float* dst = out + (size_t)row * DD + e;
#pragma unroll
      for (int r = 0; r < 4; ++r) {
        float v = acc[m][n][r];
        if (beta) v += dst[(size_t)r * DD];
        dst[(size_t)r * DD] = v;
      }
    }
  }
}

extern "C" void kernel_launch(void* const* d_in, const int* in_sizes, int n_in,
                              void* d_out, int out_size, void* d_ws, size_t ws_size,
                              hipStream_t stream) {
  const float* u    = (const float*)d_in[0];  // [4,2048,512]
  const float* ev   = (const float*)d_in[1];  // [24]
  const float* evec = (const float*)d_in[2];  // [2048,24]
  const float* mp   = (const float*)d_in[3];  // [12288,512]
  float* out = (float*)d_out;
  char* ws = (char*)d_ws;

  const size_t UT_OFF  = 0;                        // 8,388,608 B
  const size_t MHT_OFF = 8388608;                  // 12,582,912 B
  const size_t AF_OFF  = 20971520;                 // 24*134*64*8*2 = 3,293,184 B
  const size_t XT_OFF  = 24264704;                 // + 8*8,388,608 = 91.4 MB total

  f16* ut    = (f16*)(ws + UT_OFF);
  f16* mht   = (f16*)(ws + MHT_OFF);
  f16* afrag = (f16*)(ws + AF_OFF);
  f16* xt    = (f16*)(ws + XT_OFF);

  k_afrag<<<dim3(24, NPP), 64, 0, stream>>>(ev, evec, afrag);
  k_tu<<<dim3(SL / 32, DD / 32, BSZ), dim3(32, 8), 0, stream>>>(u, ut);
  k_tm<<<dim3((NK * DD) / 32, DD / 32), dim3(32, 8), 0, stream>>>(mp, mht);

  for (int c = 0; c < NK / KI; ++c) {
    k_conv<<<dim3(32, KI, BSZ), 256, 0, stream>>>(ut, afrag, xt, c * KI);
    k_gemm<<<dim3(DD / 128, (BSZ * SL) / 64), 256, 0, stream>>>(
        xt, mht, out, c * KI * DD, c > 0);
  }
}

// Round 10
// 412.524 us; speedup vs baseline: 1.8175x; 1.0387x over previous
//
#include <hip/hip_runtime.h>

typedef _Float16 f16;
typedef _Float16 f16x8 __attribute__((ext_vector_type(8)));
typedef float    f32x4 __attribute__((ext_vector_type(4)));

#define BSZ 4
#define SL  2048
#define NK  24
#define DD  512
#define NPP 134   // p' in [0,133]
#define KI  8     // i's per chunk (xt chunk 67 MB -> L3-resident)

typedef const void GV __attribute__((address_space(1)));
typedef void       LV __attribute__((address_space(3)));

__device__ __forceinline__ void gload_lds16(const void* gp, void* lp) {
  // dest = lp (wave-uniform) + lane*16
  __builtin_amdgcn_global_load_lds((GV*)gp, (LV*)lp, 16, 0, 0);
}

// ---------------- prep: A-fragment table
// afrag[i][p'][lane][j] = val(2047 - 16*(p'-6) - (lane&15) + 8*(lane>>4) + j)
// val(x) = (0<=x<2048) ? v[2047-x, i] * lam_i^0.25 : 0
__global__ void k_afrag(const float* __restrict__ eig_vals,
                        const float* __restrict__ eig_vecs,
                        f16* __restrict__ afrag) {
  int i = blockIdx.x, pp = blockIdx.y;
  int l = threadIdx.x;  // 64
  float sc = sqrtf(sqrtf(eig_vals[i]));
  int base = 2047 - 16 * (pp - 6) - (l & 15) + 8 * (l >> 4);
  f16 tmp[8];
#pragma unroll
  for (int j = 0; j < 8; ++j) {
    int x = base + j;
    float v = (x >= 0 && x < SL) ? eig_vecs[(size_t)(SL - 1 - x) * NK + i] * sc : 0.f;
    tmp[j] = (f16)v;
  }
  *(f16x8*)(afrag + (((size_t)i * NPP + pp) * 64 + l) * 8) = *(const f16x8*)tmp;
}

// ---------------- prep: ut[b][d][s] = (f16) u[b][s][d]
__global__ void k_tu(const float* __restrict__ u, f16* __restrict__ ut) {
  __shared__ float tile[32][33];
  int b = blockIdx.z;
  int s0 = blockIdx.x * 32, d0 = blockIdx.y * 32;
  int tx = threadIdx.x, ty = threadIdx.y;
#pragma unroll
  for (int r = 0; r < 4; ++r) {
    int s = s0 + ty * 4 + r;
    tile[ty * 4 + r][tx] = u[((size_t)b * SL + s) * DD + d0 + tx];
  }
  __syncthreads();
#pragma unroll
  for (int r = 0; r < 4; ++r) {
    int d = d0 + ty * 4 + r;
    ut[((size_t)b * DD + d) * SL + s0 + tx] = (f16)tile[tx][ty * 4 + r];
  }
}

// ---------------- prep: mht[e][k] = (f16) m_phi[k][e]   (B^T layout)
__global__ void k_tm(const float* __restrict__ mp, f16* __restrict__ mht) {
  __shared__ float tile[32][33];
  int k0 = blockIdx.x * 32, e0 = blockIdx.y * 32;
  int tx = threadIdx.x, ty = threadIdx.y;
#pragma unroll
  for (int r = 0; r < 4; ++r)
    tile[ty * 4 + r][tx] = mp[(size_t)(k0 + ty * 4 + r) * DD + e0 + tx];
  __syncthreads();
#pragma unroll
  for (int r = 0; r < 4; ++r)
    mht[(size_t)(e0 + ty * 4 + r) * (NK * DD) + k0 + tx] = (f16)tile[tx][ty * 4 + r];
}

// ---------------- phase A: causal Toeplitz conv -> xt[b][t][iL*512+d] (fp16, chunk-local)
// grid (32, KI, 4); 256 threads (4 waves), wave tile 128t x 64d.
// Balanced decode tb=(lin>>6)&15. 3-buffer LDS pipeline for B (depth-2),
// register sliding window for A (depth-1: 2 fresh frags/iter, rotate by 2),
// ONE raw s_barrier/iter with counted vmcnt(6) — nothing waits at issue, all drains counted.
__global__ __launch_bounds__(256, 2) void k_conv(
    const f16* __restrict__ ut, const f16* __restrict__ afrag,
    f16* __restrict__ xt, int ibase) {
  __shared__ f16 bt[3][256 * 32];   // 48 KB
  const int tid = threadIdx.x;
  const int lin = blockIdx.x + (blockIdx.y << 5) + (blockIdx.z << 8);
  const int tb = (lin >> 6) & 15;
  const int dh = lin & 1;
  const int iL = (lin >> 1) & 7;
  const int b  = (lin >> 4) & 3;
  const int iG = ibase + iL;
  const int t0 = tb * 128;

  const int w = tid >> 6, l = tid & 63;
  const int l15 = l & 15, lq = l >> 4;
  // staging/read swizzle pair (R4-proven, conflicts = 0)
  const int stage_col = ((l & 3) ^ ((l >> 3) & 3)) * 8;
  const int stage_row = l >> 2;
  const int rd_x = (lq ^ ((l15 >> 1) & 3)) * 16;

  const f16* utb = ut + (size_t)b * DD * SL;
  const f16* afi = afrag + ((size_t)iG * NPP * 64 + l) * 8;

  auto stage = [&](int buf, int s0) {
#pragma unroll
    for (int j = 0; j < 4; ++j) {
      int row = w * 64 + j * 16 + stage_row;
      gload_lds16(utb + (size_t)(dh * 256 + row) * SL + s0 + stage_col,
                  &bt[buf][(w * 64 + j * 16) * 32]);
    }
  };

  f32x4 acc[8][4];
#pragma unroll
  for (int m = 0; m < 8; ++m)
#pragma unroll
    for (int n = 0; n < 4; ++n) acc[m][n] = (f32x4){0.f, 0.f, 0.f, 0.f};

  const int nIter = 4 * (tb + 1);   // >= 4
  int pp0 = 8 * tb + 6;

  // prologue: stage0, full A window (8), stage1; drain all but stage1 -> vmcnt(4)
  stage(0, 0);
  f16x8 A[8];
#pragma unroll
  for (int m = 0; m < 8; ++m)
    A[m] = *(const f16x8*)(afi + (size_t)(pp0 + m) * 512);
  stage(1, 32);
  asm volatile("s_waitcnt vmcnt(4)" ::: "memory");   // buf0 + A window ready; stage1 in flight
  __builtin_amdgcn_s_barrier();
  __builtin_amdgcn_sched_barrier(0);

  for (int it = 0; it < nIter; ++it) {
    const int bufR = it % 3;
    // B frags from LDS (staged >= 2 iters ago, drained by prior vmcnt+barrier)
    f16x8 B[4];
#pragma unroll
    for (int n = 0; n < 4; ++n) {
      int row = w * 64 + n * 16 + l15;
      B[n] = *(const f16x8*)((const char*)&bt[bufR][0] + row * 64 + rd_x);
    }
    // A depth-1 prefetch for it+1 (window slides by 2); tail clamp, values unused
    int ppn = pp0 - 2; if (ppn < 0) ppn = 0;
    const f16* f = afi + (size_t)ppn * 512;
    f16x8 a0n = *(const f16x8*)f;
    f16x8 a1n = *(const f16x8*)(f + 512);
    // B depth-2 prefetch (buffer read at it-1; all waves passed barrier it-1)
    if (it + 2 < nIter) stage((it + 2) % 3, (it + 2) * 32);

    // keep newest 6 (this iter: 2 A-pre + 4 stage); drains prev iter's stage + A-pre
    asm volatile("s_waitcnt vmcnt(6)" ::: "memory");
    __builtin_amdgcn_s_barrier();
    __builtin_amdgcn_sched_barrier(0);

    __builtin_amdgcn_s_setprio(1);
#pragma unroll
    for (int m = 0; m < 8; ++m)
#pragma unroll
      for (int n = 0; n < 4; ++n)
        acc[m][n] = __builtin_amdgcn_mfma_f32_16x16x32_f16(A[m], B[n], acc[m][n], 0, 0, 0);
    __builtin_amdgcn_s_setprio(0);

    // rotate A window (static indices; regalloc renames)
    A[7] = A[5]; A[6] = A[4]; A[5] = A[3]; A[4] = A[2]; A[3] = A[1]; A[2] = A[0];
    A[0] = a0n;  A[1] = a1n;
    pp0 = ppn;
  }

  // store xt fp16 (regular stores: keep chunk L3-hot for the following gemm)
  // D frag: col=lane&15 (d), row=(lane>>4)*4+r (t)
  const size_t rowlen = (size_t)KI * DD;
  const int dbase = dh * 256 + w * 64;
#pragma unroll
  for (int m = 0; m < 8; ++m) {
    int t = t0 + m * 16 + lq * 4;
#pragma unroll
    for (int n = 0; n < 4; ++n) {
      int d = dbase + n * 16 + l15;
      f16* dst = xt + ((size_t)(b * SL + t) * KI + iL) * DD + d;
#pragma unroll
      for (int r = 0; r < 4; ++r)
        dst[(size_t)r * rowlen] = (f16)acc[m][n][r];
    }
  }
}

// ---------------- phase B: out[8192][512] (+)= xt[8192][4096] @ mht[:, kc0:+4096]^T
// BM=64, BN=128, BK=64; grid (4, 128) = 512 blocks (2/CU); 256 thr, 4 waves (2m x 2n)
// 3-buffer counted-vmcnt pipeline (6 loads/stage -> vmcnt(6)).
__global__ __launch_bounds__(256, 2) void k_gemm(
    const f16* __restrict__ xt, const f16* __restrict__ mht,
    float* __restrict__ out, int kc0, int beta) {
  __shared__ f16 at[3][64 * 64];      // 24 KB
  __shared__ f16 btl[3][128 * 64];    // 48 KB
  const int AK = KI * DD;             // 4096
  const int tid = threadIdx.x;
  const int n0 = blockIdx.x * 128;
  const int m0 = blockIdx.y * 64;
  const int w = tid >> 6, l = tid & 63;
  const int l15 = l & 15, lq = l >> 4;
  const int wm = w >> 1, wn = w & 1;
  const int stage_col = ((l & 7) ^ (l >> 3)) * 8;
  const int stage_row = l >> 3;

  auto stage = [&](int buf, int k0) {
#pragma unroll
    for (int j = 0; j < 2; ++j) {  // A tile [64][64]
      int row = (w * 2 + j) * 8 + stage_row;
      gload_lds16(xt + (size_t)(m0 + row) * AK + k0 + stage_col,
                  &at[buf][(w * 2 + j) * 8 * 64]);
    }
#pragma unroll
    for (int j = 0; j < 4; ++j) {  // B tile [128][64]
      int row = (w * 4 + j) * 8 + stage_row;
      gload_lds16(mht + (size_t)(n0 + row) * (NK * DD) + kc0 + k0 + stage_col,
                  &btl[buf][(w * 4 + j) * 8 * 64]);
    }
  };

  f32x4 acc[2][4];
#pragma unroll
  for (int m = 0; m < 2; ++m)
#pragma unroll
    for (int n = 0; n < 4; ++n) acc[m][n] = (f32x4){0.f, 0.f, 0.f, 0.f};

  const int nIter = AK / 64;   // 64
  stage(0, 0);
  stage(1, 64);
  asm volatile("s_waitcnt vmcnt(6)" ::: "memory");
  __builtin_amdgcn_s_barrier();
  __builtin_amdgcn_sched_barrier(0);

  for (int it = 0; it < nIter; ++it) {
    const int bufR = it % 3;
    f16x8 Af[2][2], Bf[2][4];
#pragma unroll
    for (int ks = 0; ks < 2; ++ks) {
#pragma unroll
      for (int m = 0; m < 2; ++m) {
        int lin2 = (wm * 32 + m * 16 + l15) * 128 + ks * 64 + lq * 16;
        lin2 ^= (l15 & 7) << 4;
        Af[ks][m] = *(const f16x8*)((const char*)&at[bufR][0] + lin2);
      }
#pragma unroll
      for (int n = 0; n < 4; ++n) {
        int lin2 = (wn * 64 + n * 16 + l15) * 128 + ks * 64 + lq * 16;
        lin2 ^= (l15 & 7) << 4;
        Bf[ks][n] = *(const f16x8*)((const char*)&btl[bufR][0] + lin2);
      }
    }

    if (it + 2 < nIter) stage((it + 2) % 3, (it + 2) * 64);

    asm volatile("s_waitcnt vmcnt(6)" ::: "memory");
    __builtin_amdgcn_s_barrier();
    __builtin_amdgcn_sched_barrier(0);

    __builtin_amdgcn_s_setprio(1);
#pragma unroll
    for (int ks = 0; ks < 2; ++ks)
#pragma unroll
      for (int m = 0; m < 2; ++m)
#pragma unroll
        for (int n = 0; n < 4; ++n)
          acc[m][n] = __builtin_amdgcn_mfma_f32_16x16x32_f16(
              Af[ks][m], Bf[ks][n], acc[m][n], 0, 0, 0);
    __builtin_amdgcn_s_setprio(0);
  }

#pragma unroll
  for (int m = 0; m < 2; ++m) {
    int row = m0 + wm * 32 + m * 16 + lq * 4;
#pragma unroll
    for (int n = 0; n < 4; ++n) {
      int e = n0 + wn * 64 + n * 16 + l15;
      float* dst = out + (size_t)row * DD + e;
#pragma unroll
      for (int r = 0; r < 4; ++r) {
        float v = acc[m][n][r];
        if (beta) v += dst[(size_t)r * DD];
        dst[(size_t)r * DD] = v;
      }
    }
  }
}

extern "C" void kernel_launch(void* const* d_in, const int* in_sizes, int n_in,
                              void* d_out, int out_size, void* d_ws, size_t ws_size,
                              hipStream_t stream) {
  const float* u    = (const float*)d_in[0];  // [4,2048,512]
  const float* ev   = (const float*)d_in[1];  // [24]
  const float* evec = (const float*)d_in[2];  // [2048,24]
  const float* mp   = (const float*)d_in[3];  // [12288,512]
  float* out = (float*)d_out;
  char* ws = (char*)d_ws;

  const size_t UT_OFF  = 0;                        // 8,388,608 B
  const size_t MHT_OFF = 8388608;                  // 12,582,912 B
  const size_t AF_OFF  = 20971520;                 // 24*134*64*8*2 = 3,293,184 B
  const size_t XT_OFF  = 24264704;                 // + 8*8,388,608 = 91.4 MB total

  f16* ut    = (f16*)(ws + UT_OFF);
  f16* mht   = (f16*)(ws + MHT_OFF);
  f16* afrag = (f16*)(ws + AF_OFF);
  f16* xt    = (f16*)(ws + XT_OFF);

  k_afrag<<<dim3(24, NPP), 64, 0, stream>>>(ev, evec, afrag);
  k_tu<<<dim3(SL / 32, DD / 32, BSZ), dim3(32, 8), 0, stream>>>(u, ut);
  k_tm<<<dim3((NK * DD) / 32, DD / 32), dim3(32, 8), 0, stream>>>(mp, mht);

  for (int c = 0; c < NK / KI; ++c) {
    k_conv<<<dim3(32, KI, BSZ), 256, 0, stream>>>(ut, afrag, xt, c * KI);
    k_gemm<<<dim3(DD / 128, (BSZ * SL) / 64), 256, 0, stream>>>(
        xt, mht, out, c * KI * DD, c > 0);
  }
}